// Round 10
// baseline (977.462 us; speedup 1.0000x reference)
//
#include <hip/hip_runtime.h>

// ---------------------------------------------------------------------------
// ConvFeatureExtractor: profile = rownorm( freq @ softmax(matches/T, axis=1)^T )
//   matches[f,i] = Thi[f,i>>6] + Tlo[f,i&63] (separable) => probs = e1 x e2.
// R10: single persistent kernel. R6's four phases (cast/tables/gemm/norm,
//   bodies verbatim) separated by device-scope grid barriers. Rationale:
//   R6 kernel-exec sums to ~100us but bench shows 162 -> ~60us of
//   inter-dispatch overhead; gemm itself is at the m97 plateau (R4/R5/R6/R8/R9
//   levers all dead). Grid 1024x256, 8KB LDS, launch_bounds(256,4) ->
//   4 blocks/CU co-resident by construction (manual barrier is safe).
//   Barrier counters live in d_ws; init is poison-proof (block0 zeroes, then
//   release-stores MAGIC; others spin on MAGIC which != 0x00.. and != 0xAA..).
// ---------------------------------------------------------------------------

typedef __bf16  bf16x8 __attribute__((ext_vector_type(8)));
typedef float   f32x4  __attribute__((ext_vector_type(4)));

#define GLD16(gp, lp)                                                          \
  __builtin_amdgcn_global_load_lds(                                            \
      (const __attribute__((address_space(1))) void*)(gp),                     \
      (__attribute__((address_space(3))) void*)(lp), 16, 0, 0)

__device__ __forceinline__ short f2bf(float x) {
  unsigned u = __float_as_uint(x);
  unsigned r = (u + 0x7fffu + ((u >> 16) & 1u)) >> 16;   // RNE
  return (short)r;
}

__device__ __forceinline__ float wave_max(float v) {
  #pragma unroll
  for (int off = 32; off; off >>= 1) v = fmaxf(v, __shfl_xor(v, off, 64));
  return v;
}
__device__ __forceinline__ float wave_sum(float v) {
  #pragma unroll
  for (int off = 32; off; off >>= 1) v += __shfl_xor(v, off, 64);
  return v;
}

#define NBLOCKS 1024u
#define MAGIC   0x13572468u

// device-scope grid barrier; ctr must be 0 before first use (block0 init).
__device__ __forceinline__ void grid_barrier(unsigned* ctr) {
  __threadfence();                 // release this block's prior writes (agent scope)
  __syncthreads();
  if (threadIdx.x == 0) {
    __hip_atomic_fetch_add(ctr, 1u, __ATOMIC_ACQ_REL, __HIP_MEMORY_SCOPE_AGENT);
    while (__hip_atomic_load(ctr, __ATOMIC_ACQUIRE, __HIP_MEMORY_SCOPE_AGENT) < NBLOCKS)
      __builtin_amdgcn_s_sleep(2);
  }
  __syncthreads();
  __threadfence();                 // acquire: see other blocks' writes
}

__global__ __launch_bounds__(256, 4)
void fused_kernel(const float* __restrict__ freq,
                  const float* __restrict__ kp,
                  const float* __restrict__ temp,
                  short* __restrict__ freqb,
                  float* __restrict__ E1t,
                  float* __restrict__ E2,
                  unsigned* __restrict__ bar,     // [0]=b1 [1]=b2 [2]=init flag
                  float* __restrict__ out) {
  __shared__ short As[64 * 64];                   // gemm tile (8 KB)
  __shared__ float red[4];

  const int blk = blockIdx.x;
  const int t = threadIdx.x;
  const int lane = t & 63, wave = t >> 6;

  // ---- barrier init (poison-proof) ----
  if (blk == 0 && t == 0) {
    __hip_atomic_store(&bar[0], 0u, __ATOMIC_RELAXED, __HIP_MEMORY_SCOPE_AGENT);
    __hip_atomic_store(&bar[1], 0u, __ATOMIC_RELAXED, __HIP_MEMORY_SCOPE_AGENT);
    __hip_atomic_store(&bar[2], MAGIC, __ATOMIC_RELEASE, __HIP_MEMORY_SCOPE_AGENT);
  }
  if (t == 0) {
    while (__hip_atomic_load(&bar[2], __ATOMIC_ACQUIRE, __HIP_MEMORY_SCOPE_AGENT) != MAGIC)
      __builtin_amdgcn_s_sleep(2);
  }
  __syncthreads();

  // ================= phase 1a: cast freq f32 -> bf16 =================
  // 4M floats = 1M float4; grid-stride: 4 float4 per thread.
  #pragma unroll
  for (int i = 0; i < 4; i++) {
    const int idx = i * (1024 * 256) + blk * 256 + t;
    float4 v = ((const float4*)freq)[idx];
    short4 o;
    o.x = f2bf(v.x); o.y = f2bf(v.y); o.z = f2bf(v.z); o.w = f2bf(v.w);
    ((short4*)freqb)[idx] = o;
  }

  // ================= phase 1b: softmax factor tables =================
  // 8 filters per block, 2 per wave. lane indexes h (e1) / l (e2).
  {
    const float invT = 1.0f / temp[0];
    const int d0 = (lane >> 4) & 3, d1 = (lane >> 2) & 3, d2 = lane & 3;
    #pragma unroll
    for (int ff = 0; ff < 2; ff++) {
      const int f = blk * 8 + wave * 2 + ff;
      const float* P = kp + (size_t)f * 24;
      const float thi = P[d0 * 6 + 0] + P[d1 * 6 + 1] + P[d2 * 6 + 2];
      const float tlo = P[d0 * 6 + 3] + P[d1 * 6 + 4] + P[d2 * 6 + 5];
      const float mxhi = wave_max(thi), mxlo = wave_max(tlo);
      const float e1 = __expf((thi - mxhi) * invT);
      const float e2 = __expf((tlo - mxlo) * invT);
      const float s1 = wave_sum(e1), s2 = wave_sum(e2);
      const float invZ = 1.0f / (s1 * s2);
      E1t[lane * 8192 + f] = e1 * invZ;
      E2[(size_t)f * 64 + lane] = e2;
    }
  }

  grid_barrier(&bar[0]);

  // ================= phase 2: GEMM (R6 body verbatim) =================
  // pooled = A(1024x4096) * B^T, B[f,i] = e1[f,i>>6]*e2[f,i&63].
  // TM=64, TN=128, BK=64; block (blk>>6) = m-tile, (blk&63) = n-tile.
  {
    const int quad = lane >> 4, l16 = lane & 15;
    const int m0 = (blk >> 6) * 64;
    const int n0 = (blk & 63) * 128;
    const int wn = wave * 32;

    f32x4 acc[4][2];
    #pragma unroll
    for (int i = 0; i < 4; i++)
      #pragma unroll
      for (int j = 0; j < 2; j++) acc[i][j] = (f32x4){0.f, 0.f, 0.f, 0.f};

    int nrow[2];
    #pragma unroll
    for (int j = 0; j < 2; j++) nrow[j] = n0 + wn + j * 16 + l16;
    float4 e2a[2][2], e2b[2][2];
    #pragma unroll
    for (int j = 0; j < 2; j++)
      #pragma unroll
      for (int ks = 0; ks < 2; ks++) {
        const float* p = E2 + (size_t)nrow[j] * 64 + (ks * 4 + quad) * 8;
        e2a[j][ks] = *(const float4*)p;
        e2b[j][ks] = *(const float4*)(p + 4);
      }

    const int lane_row = lane >> 3;                      // 0..7 within chunk
    const int src_col = ((lane & 7) ^ lane_row) * 8;     // swizzled col (shorts)
    const int sw = l16 & 7;                              // reader swizzle key

    for (int kt = 0; kt < 64; kt++) {
      const int kofs = kt * 64;
      float e1v[2];
      #pragma unroll
      for (int j = 0; j < 2; j++) e1v[j] = E1t[kt * 8192 + nrow[j]];

      __syncthreads();
      #pragma unroll
      for (int c = 0; c < 2; c++) {
        const int chunk = wave * 2 + c;                  // 0..7
        const int row = chunk * 8 + lane_row;            // 0..63
        GLD16(freqb + (m0 + row) * 4096 + kofs + src_col, &As[chunk * 512 + lane * 8]);
      }
      __syncthreads();

      bf16x8 b[2][2];
      #pragma unroll
      for (int j = 0; j < 2; j++)
        #pragma unroll
        for (int ks = 0; ks < 2; ks++) {
          const float s = e1v[j];
          bf16x8 bb;
          bb[0] = (__bf16)(s * e2a[j][ks].x);
          bb[1] = (__bf16)(s * e2a[j][ks].y);
          bb[2] = (__bf16)(s * e2a[j][ks].z);
          bb[3] = (__bf16)(s * e2a[j][ks].w);
          bb[4] = (__bf16)(s * e2b[j][ks].x);
          bb[5] = (__bf16)(s * e2b[j][ks].y);
          bb[6] = (__bf16)(s * e2b[j][ks].z);
          bb[7] = (__bf16)(s * e2b[j][ks].w);
          b[ks][j] = bb;
        }

      #pragma unroll
      for (int ks = 0; ks < 2; ks++) {
        const int pcol = ((ks * 4 + quad) ^ sw) * 8;     // physical col (shorts)
        bf16x8 a[4];
        #pragma unroll
        for (int i = 0; i < 4; i++)
          a[i] = *(const bf16x8*)&As[(i * 16 + l16) * 64 + pcol];
        #pragma unroll
        for (int i = 0; i < 4; i++)
          #pragma unroll
          for (int j = 0; j < 2; j++)
            acc[i][j] = __builtin_amdgcn_mfma_f32_16x16x32_bf16(a[i], b[ks][j], acc[i][j], 0, 0, 0);
      }
    }

    // epilogue: C/D layout col=lane&15, row=quad*4+reg
    #pragma unroll
    for (int i = 0; i < 4; i++) {
      #pragma unroll
      for (int r = 0; r < 4; r++) {
        const int brow = m0 + i * 16 + quad * 4 + r;
        float* crow = out + (size_t)brow * 8192 + n0 + wn + l16;
        #pragma unroll
        for (int j = 0; j < 2; j++) crow[j * 16] = acc[i][j][r];
      }
    }
  }

  grid_barrier(&bar[1]);

  // ================= phase 3: row-normalize (R6 body, row = blk) ==========
  {
    float4* row = (float4*)(out + (size_t)blk * 8192);   // 2048 float4
    float4 v[8];
    float s = 0.0f;
    #pragma unroll
    for (int q = 0; q < 8; q++) {
      v[q] = row[q * 256 + t];
      s += (v[q].x + v[q].y) + (v[q].z + v[q].w);
    }
    float ws = wave_sum(s);
    if (lane == 0) red[wave] = ws;
    __syncthreads();
    float tot = (red[0] + red[1]) + (red[2] + red[3]);
    float inv = 1.0f / tot;
    #pragma unroll
    for (int q = 0; q < 8; q++) {
      v[q].x *= inv; v[q].y *= inv; v[q].z *= inv; v[q].w *= inv;
      row[q * 256 + t] = v[q];
    }
  }
}

// ---------------------------------------------------------------------------
extern "C" void kernel_launch(void* const* d_in, const int* in_sizes, int n_in,
                              void* d_out, int out_size, void* d_ws, size_t ws_size,
                              hipStream_t stream) {
  const float* freq    = (const float*)d_in[0];   // 1024*4096
  const float* kparams = (const float*)d_in[1];   // 8192*4*6
  const float* temp    = (const float*)d_in[2];   // 1
  // d_in[3] = kmer_idcs (recomputed analytically in-kernel)

  float* out = (float*)d_out;                     // 1024*8192 f32

  char* ws = (char*)d_ws;
  short*    freqb = (short*)ws;                               // 8 MiB
  float*    E1t   = (float*)(ws + (size_t)8  * 1024 * 1024);  // 2 MiB
  float*    E2    = (float*)(ws + (size_t)10 * 1024 * 1024);  // 2 MiB
  unsigned* bar   = (unsigned*)(ws + (size_t)14 * 1024 * 1024);

  fused_kernel<<<NBLOCKS, 256, 0, stream>>>(freq, kparams, temp,
                                            freqb, E1t, E2, bar, out);
}

// Round 11
// 162.174 us; speedup vs baseline: 6.0272x; 6.0272x over previous
//
#include <hip/hip_runtime.h>

// ---------------------------------------------------------------------------
// ConvFeatureExtractor: profile = rownorm( freq @ softmax(matches/T, axis=1)^T )
//   matches[f,i] = Thi[f,i>>6] + Tlo[f,i&63] (separable) => probs = e1 x e2.
// R11: revert to R6 (empirical best, 162us; R7-R10 levers all regressed) with
//   one delta: tables merged into the cast kernel as blocks 0..127 (FIRST in
//   dispatch order so they overlap the cast wave, unlike R8's tail placement).
//   4 dispatches -> 3. gemm is at the m97-structure plateau (855 TF, ~41% of
//   dense): occupancy (R4/R6), staging bytes (R5), barrier count (R8), barrier
//   removal (R9), persistent fusion (R10) all proven dead.
// ---------------------------------------------------------------------------

typedef __bf16  bf16x8 __attribute__((ext_vector_type(8)));
typedef float   f32x4  __attribute__((ext_vector_type(4)));

#define GLD16(gp, lp)                                                          \
  __builtin_amdgcn_global_load_lds(                                            \
      (const __attribute__((address_space(1))) void*)(gp),                     \
      (__attribute__((address_space(3))) void*)(lp), 16, 0, 0)

__device__ __forceinline__ short f2bf(float x) {
  unsigned u = __float_as_uint(x);
  unsigned r = (u + 0x7fffu + ((u >> 16) & 1u)) >> 16;   // RNE
  return (short)r;
}

__device__ __forceinline__ float wave_max(float v) {
  #pragma unroll
  for (int off = 32; off; off >>= 1) v = fmaxf(v, __shfl_xor(v, off, 64));
  return v;
}
__device__ __forceinline__ float wave_sum(float v) {
  #pragma unroll
  for (int off = 32; off; off >>= 1) v += __shfl_xor(v, off, 64);
  return v;
}

// ---------------- k1: prep = tables (blocks 0..127) + cast (blocks 128..4223)
// tables: 64 filters/block, 16/wave; lane indexes h (e1) / l (e2).
//   E1t[h][f] = e1*invZ (4B scattered, tiny), E2[f][l] = e2 (wave-contiguous).
// cast: freq f32 -> bf16, float4 loads / short4 stores.
__global__ __launch_bounds__(256) void prep_kernel(const float* __restrict__ freq,
                                                   const float* __restrict__ kp,
                                                   const float* __restrict__ temp,
                                                   short* __restrict__ freqb,
                                                   float* __restrict__ E1t,
                                                   float* __restrict__ E2) {
  const int blk = blockIdx.x;
  const int t = threadIdx.x;

  if (blk >= 128) {                     // ---- cast part
    int idx = (blk - 128) * 256 + t;
    float4 v = ((const float4*)freq)[idx];
    short4 o;
    o.x = f2bf(v.x); o.y = f2bf(v.y); o.z = f2bf(v.z); o.w = f2bf(v.w);
    ((short4*)freqb)[idx] = o;
    return;
  }

  // ---- tables part (R6 math verbatim)
  const int lane = t & 63, wave = t >> 6;
  const float invT = 1.0f / temp[0];
  const int d0 = (lane >> 4) & 3, d1 = (lane >> 2) & 3, d2 = lane & 3;

  #pragma unroll
  for (int ffi = 0; ffi < 16; ffi++) {
    const int f = blk * 64 + wave * 16 + ffi;
    const float* P = kp + (size_t)f * 24;
    const float thi = P[d0 * 6 + 0] + P[d1 * 6 + 1] + P[d2 * 6 + 2];
    const float tlo = P[d0 * 6 + 3] + P[d1 * 6 + 4] + P[d2 * 6 + 5];
    const float mxhi = wave_max(thi), mxlo = wave_max(tlo);
    const float e1 = __expf((thi - mxhi) * invT);
    const float e2 = __expf((tlo - mxlo) * invT);
    const float s1 = wave_sum(e1), s2 = wave_sum(e2);
    const float invZ = 1.0f / (s1 * s2);
    E1t[lane * 8192 + f] = e1 * invZ;   // lane = h
    E2[(size_t)f * 64 + lane] = e2;     // lane = l
  }
}

// ---------------- k2: GEMM pooled = A(1024x4096) * B^T, B[f,i]=e1[f,i>>6]e2[f,i&63]
// (R6 body verbatim.) Tiles: TM=64, TN=128, BK=64; grid 64x16 = 1024 blocks
// (4/CU, 16 waves/CU). 4 waves side-by-side in N: wave tile 64m x 32n = 4x2
// frags of 16x16x32. Only A staged in LDS (XOR-swizzled: row stride 128B ==
// 32 banks otherwise). B built in regs: e2 frags preloaded, scaled by e1[f,kt].
__global__ __launch_bounds__(256, 4) void gemm_kernel(const short* __restrict__ A,
                                                      const float* __restrict__ E1t,
                                                      const float* __restrict__ E2,
                                                      float* __restrict__ C) {
  __shared__ short As[64 * 64];

  const int t = threadIdx.x;
  const int lane = t & 63, wave = t >> 6;
  const int quad = lane >> 4, l16 = lane & 15;
  const int m0 = blockIdx.y * 64;        // batch tile
  const int n0 = blockIdx.x * 128;       // filter tile
  const int wn = wave * 32;              // wave's n-offset within tile

  f32x4 acc[4][2];
  #pragma unroll
  for (int i = 0; i < 4; i++)
    #pragma unroll
    for (int j = 0; j < 2; j++) acc[i][j] = (f32x4){0.f, 0.f, 0.f, 0.f};

  int nrow[2];
  #pragma unroll
  for (int j = 0; j < 2; j++) nrow[j] = n0 + wn + j * 16 + l16;
  float4 e2a[2][2], e2b[2][2];
  #pragma unroll
  for (int j = 0; j < 2; j++)
    #pragma unroll
    for (int ks = 0; ks < 2; ks++) {
      const float* p = E2 + (size_t)nrow[j] * 64 + (ks * 4 + quad) * 8;
      e2a[j][ks] = *(const float4*)p;
      e2b[j][ks] = *(const float4*)(p + 4);
    }

  const int lane_row = lane >> 3;                      // 0..7 within chunk
  const int src_col = ((lane & 7) ^ lane_row) * 8;     // swizzled global col (shorts)
  const int sw = l16 & 7;                              // reader swizzle key (= row&7)

  for (int kt = 0; kt < 64; kt++) {
    const int kofs = kt * 64;
    float e1v[2];
    #pragma unroll
    for (int j = 0; j < 2; j++) e1v[j] = E1t[kt * 8192 + nrow[j]];

    __syncthreads();
    #pragma unroll
    for (int c = 0; c < 2; c++) {
      const int chunk = wave * 2 + c;                  // 0..7
      const int row = chunk * 8 + lane_row;            // 0..63
      GLD16(A + (m0 + row) * 4096 + kofs + src_col, &As[chunk * 512 + lane * 8]);
    }
    __syncthreads();

    bf16x8 b[2][2];
    #pragma unroll
    for (int j = 0; j < 2; j++)
      #pragma unroll
      for (int ks = 0; ks < 2; ks++) {
        const float s = e1v[j];
        bf16x8 bb;
        bb[0] = (__bf16)(s * e2a[j][ks].x);
        bb[1] = (__bf16)(s * e2a[j][ks].y);
        bb[2] = (__bf16)(s * e2a[j][ks].z);
        bb[3] = (__bf16)(s * e2a[j][ks].w);
        bb[4] = (__bf16)(s * e2b[j][ks].x);
        bb[5] = (__bf16)(s * e2b[j][ks].y);
        bb[6] = (__bf16)(s * e2b[j][ks].z);
        bb[7] = (__bf16)(s * e2b[j][ks].w);
        b[ks][j] = bb;
      }

    #pragma unroll
    for (int ks = 0; ks < 2; ks++) {
      const int pcol = ((ks * 4 + quad) ^ sw) * 8;     // physical col (shorts)
      bf16x8 a[4];
      #pragma unroll
      for (int i = 0; i < 4; i++)
        a[i] = *(const bf16x8*)&As[(i * 16 + l16) * 64 + pcol];
      #pragma unroll
      for (int i = 0; i < 4; i++)
        #pragma unroll
        for (int j = 0; j < 2; j++)
          acc[i][j] = __builtin_amdgcn_mfma_f32_16x16x32_bf16(a[i], b[ks][j], acc[i][j], 0, 0, 0);
    }
  }

  // epilogue: C/D layout col=lane&15, row=quad*4+reg
  #pragma unroll
  for (int i = 0; i < 4; i++) {
    #pragma unroll
    for (int r = 0; r < 4; r++) {
      const int brow = m0 + i * 16 + quad * 4 + r;
      float* crow = C + (size_t)brow * 8192 + n0 + wn + l16;
      #pragma unroll
      for (int j = 0; j < 2; j++) crow[j * 16] = acc[i][j][r];
    }
  }
}

// ---------------- k3: row-normalize d_out (1024 rows of 8192) ----------------
__global__ __launch_bounds__(256) void norm_kernel(float* __restrict__ out) {
  const int b = blockIdx.x;
  const int t = threadIdx.x;
  const int lane = t & 63, wave = t >> 6;
  __shared__ float red[4];

  float4* row = (float4*)(out + (size_t)b * 8192);   // 2048 float4
  float4 v[8];
  float s = 0.0f;
  #pragma unroll
  for (int q = 0; q < 8; q++) {
    v[q] = row[q * 256 + t];
    s += (v[q].x + v[q].y) + (v[q].z + v[q].w);
  }
  float ws = wave_sum(s);
  if (lane == 0) red[wave] = ws;
  __syncthreads();
  float tot = (red[0] + red[1]) + (red[2] + red[3]);
  float inv = 1.0f / tot;
  #pragma unroll
  for (int q = 0; q < 8; q++) {
    v[q].x *= inv; v[q].y *= inv; v[q].z *= inv; v[q].w *= inv;
    row[q * 256 + t] = v[q];
  }
}

// ---------------------------------------------------------------------------
extern "C" void kernel_launch(void* const* d_in, const int* in_sizes, int n_in,
                              void* d_out, int out_size, void* d_ws, size_t ws_size,
                              hipStream_t stream) {
  const float* freq    = (const float*)d_in[0];   // 1024*4096
  const float* kparams = (const float*)d_in[1];   // 8192*4*6
  const float* temp    = (const float*)d_in[2];   // 1
  // d_in[3] = kmer_idcs (recomputed analytically in-kernel)

  float* out = (float*)d_out;                     // 1024*8192 f32

  short* freqb = (short*)d_ws;                           // 8 MiB
  float* E1t   = (float*)(freqb + (size_t)1024 * 4096);  // 64*8192 f32 = 2 MiB
  float* E2    = E1t + (size_t)64 * 8192;                // 8192*64 f32 = 2 MiB

  prep_kernel<<<4224, 256, 0, stream>>>(freq, kparams, temp, freqb, E1t, E2);
  gemm_kernel<<<dim3(64, 16), 256, 0, stream>>>(freqb, E1t, E2, out);
  norm_kernel<<<1024, 256, 0, stream>>>(out);
}